// Round 10
// baseline (33125.925 us; speedup 1.0000x reference)
//
#include <hip/hip_runtime.h>

#define T_STEPS 65536
#define NIN 99
#define HID 64
#define G4 256   // 4*HID gates
#define TS 128   // timesteps per block in the projection kernel

// ---------------- Kernel 1: xz2[t][unit][4] = gates (i,f,g,o) of unit ----------------
__global__ __launch_bounds__(256, 1) void xz_kernel(
    const float* __restrict__ x, const float* __restrict__ W_ih,
    const float* __restrict__ b_ih, const float* __restrict__ b_hh,
    float* __restrict__ xz2) {
    __shared__ __align__(16) float xs[TS * 100];   // padded rows: 400 B stride
    const int g  = threadIdx.x;                    // gate row 0..255
    const int t0 = blockIdx.x * TS;
    const int unit = g & 63, d = g >> 6;           // transposed write position

    for (int i = g; i < TS * NIN; i += 256) {
        int tl = i / NIN;
        int j  = i - tl * NIN;
        xs[tl * 100 + j] = x[(size_t)t0 * NIN + i];
    }

    float w[NIN];
#pragma unroll
    for (int j = 0; j < NIN; ++j) w[j] = W_ih[g * NIN + j];
    const float bias = b_ih[g] + b_hh[g];
    __syncthreads();

    for (int tl = 0; tl < TS; ++tl) {
        const float* xr = &xs[tl * 100];
        float a0 = bias, a1 = 0.f, a2 = 0.f, a3 = 0.f;
#pragma unroll
        for (int j4 = 0; j4 < 24; ++j4) {
            float4 xv = *(const float4*)(xr + 4 * j4);
            a0 = fmaf(w[4 * j4 + 0], xv.x, a0);
            a1 = fmaf(w[4 * j4 + 1], xv.y, a1);
            a2 = fmaf(w[4 * j4 + 2], xv.z, a2);
            a3 = fmaf(w[4 * j4 + 3], xv.w, a3);
        }
        a0 = fmaf(w[96], xr[96], a0);
        a1 = fmaf(w[97], xr[97], a1);
        a2 = fmaf(w[98], xr[98], a2);
        xz2[(size_t)(t0 + tl) * G4 + unit * 4 + d] = (a0 + a1) + (a2 + a3);
    }
}

// ---------------- Kernel 2: full-asm split-K LSTM recurrence ----------------
// R7 structure (4 waves, unit-major, 16-wide k-chunk per wave), but the entire
// K-loop is ONE asm block with hard-coded physical registers:
//   v100-v163 : W_hh fragment (i:100-115, f:116-131, g:132-147, o:148-163)
//   v196/v197 : h / c        v199 : rolling z byte-offset
//   v200-203  : gate accumulators (adjacent -> ds_write_b128)
//   v204-215  : partner partials (3x ds_read_b128)
//   v216-223  : activation scratch    v224-239 : 4-quad z prefetch ring
// Per step: 16 v_readlane + 64 v_fmac, ds_write_b128, lgkm-only barrier,
// 3x ds_read_b128, s_waitcnt vmcnt(3) (prefetch never drained), activations.
// This removes the compiler's AGPR parking + copy traffic (R2-R9: VGPR stuck
// at 48-100, ~350 extra VALU cyc/step of accvgpr copies).

#define RLN(SD) \
  "v_readlane_b32 " SD ", v196, s82\n\t" \
  "s_add_u32 s82, s82, 1\n\t"

#define G4A(SH, RI, RF, RG, RO) \
  "v_fmac_f32 v200, " SH ", " RI "\n\t" \
  "v_fmac_f32 v201, " SH ", " RF "\n\t" \
  "v_fmac_f32 v202, " SH ", " RG "\n\t" \
  "v_fmac_f32 v203, " SH ", " RO "\n\t"

#define PHASE1 \
  "s_mov_b32 s82, %[sb]\n\t" \
  RLN("s80") RLN("s81") \
  "v_mul_f32 v200, s80, v100\n\t" \
  "v_mul_f32 v201, s80, v116\n\t" \
  "v_mul_f32 v202, s80, v132\n\t" \
  "v_mul_f32 v203, s80, v148\n\t" \
  RLN("s80") G4A("s81","v101","v117","v133","v149") \
  RLN("s81") G4A("s80","v102","v118","v134","v150") \
  RLN("s80") G4A("s81","v103","v119","v135","v151") \
  RLN("s81") G4A("s80","v104","v120","v136","v152") \
  RLN("s80") G4A("s81","v105","v121","v137","v153") \
  RLN("s81") G4A("s80","v106","v122","v138","v154") \
  RLN("s80") G4A("s81","v107","v123","v139","v155") \
  RLN("s81") G4A("s80","v108","v124","v140","v156") \
  RLN("s80") G4A("s81","v109","v125","v141","v157") \
  RLN("s81") G4A("s80","v110","v126","v142","v158") \
  RLN("s80") G4A("s81","v111","v127","v143","v159") \
  RLN("s81") G4A("s80","v112","v128","v144","v160") \
  RLN("s80") G4A("s81","v113","v129","v145","v161") \
  RLN("s81") G4A("s80","v114","v130","v146","v162") \
  G4A("s81","v115","v131","v147","v163")

#define PHASE2(OFS, ZQ, Z0, Z1, Z2, Z3) \
  "ds_write_b128 %[wa], v[200:203] offset:" OFS "\n\t" \
  "s_waitcnt lgkmcnt(0)\n\t" \
  "s_barrier\n\t" \
  "ds_read_b128 v[204:207], %[ra0] offset:" OFS "\n\t" \
  "ds_read_b128 v[208:211], %[ra1] offset:" OFS "\n\t" \
  "ds_read_b128 v[212:215], %[ra2] offset:" OFS "\n\t" \
  "s_waitcnt vmcnt(3)\n\t" \
  "v_add_f32 v200, v200, " Z0 "\n\t" \
  "v_add_f32 v201, v201, " Z1 "\n\t" \
  "v_add_f32 v202, v202, " Z2 "\n\t" \
  "v_add_f32 v203, v203, " Z3 "\n\t" \
  "global_load_dwordx4 " ZQ ", v199, %[zb]\n\t" \
  "v_add_u32 v199, 0x400, v199\n\t" \
  "v_cmp_gt_u32 vcc, 0x4000000, v199\n\t" \
  "v_cndmask_b32 v199, %[zoff], v199, vcc\n\t" \
  "s_waitcnt lgkmcnt(0)\n\t" \
  "v_add_f32 v200, v200, v204\n\t" \
  "v_add_f32 v201, v201, v205\n\t" \
  "v_add_f32 v202, v202, v206\n\t" \
  "v_add_f32 v203, v203, v207\n\t" \
  "v_add_f32 v200, v200, v208\n\t" \
  "v_add_f32 v201, v201, v209\n\t" \
  "v_add_f32 v202, v202, v210\n\t" \
  "v_add_f32 v203, v203, v211\n\t" \
  "v_add_f32 v200, v200, v212\n\t" \
  "v_add_f32 v201, v201, v213\n\t" \
  "v_add_f32 v202, v202, v214\n\t" \
  "v_add_f32 v203, v203, v215\n\t" \
  "v_mul_f32 v216, 0xbfb8aa3b, v200\n\t" \
  "v_mul_f32 v217, 0xbfb8aa3b, v201\n\t" \
  "v_mul_f32 v218, 0xbfb8aa3b, v203\n\t" \
  "v_and_b32 v219, 0x7fffffff, v202\n\t" \
  "v_exp_f32 v216, v216\n\t" \
  "v_exp_f32 v217, v217\n\t" \
  "v_exp_f32 v218, v218\n\t" \
  "v_mul_f32 v219, 0x4038aa3b, v219\n\t" \
  "v_exp_f32 v219, v219\n\t" \
  "v_add_f32 v216, 1.0, v216\n\t" \
  "v_add_f32 v217, 1.0, v217\n\t" \
  "v_add_f32 v218, 1.0, v218\n\t" \
  "v_add_f32 v219, 1.0, v219\n\t" \
  "v_rcp_f32 v216, v216\n\t" \
  "v_rcp_f32 v217, v217\n\t" \
  "v_rcp_f32 v219, v219\n\t" \
  "v_rcp_f32 v218, v218\n\t" \
  "v_fma_f32 v219, -2.0, v219, 1.0\n\t" \
  "v_bfi_b32 v219, s84, v202, v219\n\t" \
  "v_mul_f32 v220, v216, v219\n\t" \
  "v_fma_f32 v197, v217, v197, v220\n\t" \
  "v_and_b32 v221, 0x7fffffff, v197\n\t" \
  "v_mul_f32 v221, 0x4038aa3b, v221\n\t" \
  "v_exp_f32 v221, v221\n\t" \
  "s_nop 0\n\t" \
  "v_add_f32 v221, 1.0, v221\n\t" \
  "v_rcp_f32 v221, v221\n\t" \
  "s_nop 0\n\t" \
  "v_fma_f32 v221, -2.0, v221, 1.0\n\t" \
  "v_bfi_b32 v221, s84, v197, v221\n\t" \
  "v_mul_f32 v196, v218, v221\n\t"

__global__ __launch_bounds__(256, 1) __attribute__((amdgpu_waves_per_eu(1)))
void lstm_kernel(
    const float* __restrict__ xz2, const float* __restrict__ W_hh,
    const float* __restrict__ W1, const float* __restrict__ W2,
    const float* __restrict__ b2, float* __restrict__ out) {
    __shared__ __align__(16) float pbuf[2][4][HID][4];   // [parity][chunk][unit][gate]
    __shared__ float hfin[HID];
    __shared__ float hbuf[32];
    const int tid = threadIdx.x;
    const int l   = tid & 63;
    const int wv  = tid >> 6;

    // byte offsets / addresses for the asm block
    unsigned woff = (unsigned)(l * 256 + wv * 64);      // W_hh: row l, col 16wv
    unsigned zoff = (unsigned)(l * 16);                 // xz2: unit l's float4
    unsigned lbase = (unsigned)(size_t)&pbuf[0][0][0][0];
    unsigned wa  = lbase + (unsigned)((wv * 64 + l) * 16);
    unsigned ra0 = lbase + (unsigned)((((wv + 1) & 3) * 64 + l) * 16);
    unsigned ra1 = lbase + (unsigned)((((wv + 2) & 3) * 64 + l) * 16);
    unsigned ra2 = lbase + (unsigned)((((wv + 3) & 3) * 64 + l) * 16);
    int ssb = __builtin_amdgcn_readfirstlane(16 * wv);  // k-chunk base lane

    float h;
    asm volatile(
        // ---- prologue: h=c=0, constants, weight + z-ring loads ----
        "v_mov_b32 v196, 0\n\t"
        "v_mov_b32 v197, 0\n\t"
        "s_mov_b32 s84, 0x80000000\n\t"
        "v_mov_b32 v199, %[woff]\n\t"
        "global_load_dwordx4 v[100:103], v199, %[wb]\n\t"
        "global_load_dwordx4 v[104:107], v199, %[wb] offset:16\n\t"
        "global_load_dwordx4 v[108:111], v199, %[wb] offset:32\n\t"
        "global_load_dwordx4 v[112:115], v199, %[wb] offset:48\n\t"
        "v_add_u32 v199, 0x4000, v199\n\t"
        "global_load_dwordx4 v[116:119], v199, %[wb]\n\t"
        "global_load_dwordx4 v[120:123], v199, %[wb] offset:16\n\t"
        "global_load_dwordx4 v[124:127], v199, %[wb] offset:32\n\t"
        "global_load_dwordx4 v[128:131], v199, %[wb] offset:48\n\t"
        "v_add_u32 v199, 0x4000, v199\n\t"
        "global_load_dwordx4 v[132:135], v199, %[wb]\n\t"
        "global_load_dwordx4 v[136:139], v199, %[wb] offset:16\n\t"
        "global_load_dwordx4 v[140:143], v199, %[wb] offset:32\n\t"
        "global_load_dwordx4 v[144:147], v199, %[wb] offset:48\n\t"
        "v_add_u32 v199, 0x4000, v199\n\t"
        "global_load_dwordx4 v[148:151], v199, %[wb]\n\t"
        "global_load_dwordx4 v[152:155], v199, %[wb] offset:16\n\t"
        "global_load_dwordx4 v[156:159], v199, %[wb] offset:32\n\t"
        "global_load_dwordx4 v[160:163], v199, %[wb] offset:48\n\t"
        "v_mov_b32 v199, %[zoff]\n\t"
        "global_load_dwordx4 v[224:227], v199, %[zb]\n\t"
        "global_load_dwordx4 v[228:231], v199, %[zb] offset:1024\n\t"
        "global_load_dwordx4 v[232:235], v199, %[zb] offset:2048\n\t"
        "global_load_dwordx4 v[236:239], v199, %[zb] offset:3072\n\t"
        "v_add_u32 v199, 0x1000, v199\n\t"
        "s_waitcnt vmcnt(4)\n\t"            // weights resident; z ring in flight
        "s_mov_b32 s85, 0x4000\n\t"         // 16384 iterations x 4 steps
        "Lk%=:\n\t"
        PHASE1 PHASE2("0",    "v[224:227]", "v224", "v225", "v226", "v227")
        PHASE1 PHASE2("4096", "v[228:231]", "v228", "v229", "v230", "v231")
        PHASE1 PHASE2("0",    "v[232:235]", "v232", "v233", "v234", "v235")
        PHASE1 PHASE2("4096", "v[236:239]", "v236", "v237", "v238", "v239")
        "s_sub_u32 s85, s85, 1\n\t"
        "s_cmp_lg_u32 s85, 0\n\t"
        "s_cbranch_scc1 Lk%=\n\t"
        "v_mov_b32 %[hout], v196\n\t"
        : [hout]"=v"(h)
        : [wb]"s"(W_hh), [zb]"s"(xz2), [sb]"s"(ssb),
          [woff]"v"(woff), [zoff]"v"(zoff),
          [wa]"v"(wa), [ra0]"v"(ra0), [ra1]"v"(ra1), [ra2]"v"(ra2)
        : "memory", "vcc",
          "s80","s81","s82","s83","s84","s85",
          "v100","v101","v102","v103","v104","v105","v106","v107",
          "v108","v109","v110","v111","v112","v113","v114","v115",
          "v116","v117","v118","v119","v120","v121","v122","v123",
          "v124","v125","v126","v127","v128","v129","v130","v131",
          "v132","v133","v134","v135","v136","v137","v138","v139",
          "v140","v141","v142","v143","v144","v145","v146","v147",
          "v148","v149","v150","v151","v152","v153","v154","v155",
          "v156","v157","v158","v159","v160","v161","v162","v163",
          "v196","v197","v198","v199",
          "v200","v201","v202","v203","v204","v205","v206","v207",
          "v208","v209","v210","v211","v212","v213","v214","v215",
          "v216","v217","v218","v219","v220","v221","v222","v223",
          "v224","v225","v226","v227","v228","v229","v230","v231",
          "v232","v233","v234","v235","v236","v237","v238","v239");

    // head: out = W2 @ relu(W1 @ relu(h_T)) + b2
    if (tid < HID) hfin[tid] = h;
    __syncthreads();
    if (tid < 32) {
        float s = 0.0f;
#pragma unroll
        for (int j = 0; j < HID; ++j) s += W1[tid * HID + j] * fmaxf(hfin[j], 0.0f);
        hbuf[tid] = fmaxf(s, 0.0f);
    }
    __syncthreads();
    if (tid < 3) {
        float s = b2[tid];
#pragma unroll
        for (int j = 0; j < 32; ++j) s += W2[tid * 32 + j] * hbuf[j];
        out[tid] = s;
    }
}

extern "C" void kernel_launch(void* const* d_in, const int* in_sizes, int n_in,
                              void* d_out, int out_size, void* d_ws, size_t ws_size,
                              hipStream_t stream) {
    const float* x   = (const float*)d_in[0];
    const float* Wih = (const float*)d_in[1];
    const float* Whh = (const float*)d_in[2];
    const float* bih = (const float*)d_in[3];
    const float* bhh = (const float*)d_in[4];
    const float* W1  = (const float*)d_in[5];
    const float* W2  = (const float*)d_in[6];
    const float* b2  = (const float*)d_in[7];
    float* out = (float*)d_out;
    float* xz2 = (float*)d_ws;   // T_STEPS * 256 floats = 64 MB (transposed layout)

    xz_kernel<<<T_STEPS / TS, 256, 0, stream>>>(x, Wih, bih, bhh, xz2);
    lstm_kernel<<<1, 256, 0, stream>>>(xz2, Whh, W1, W2, b2, out);
}

// Round 11
// 24470.825 us; speedup vs baseline: 1.3537x; 1.3537x over previous
//
#include <hip/hip_runtime.h>

#define T_STEPS 65536
#define NIN 99
#define HID 64
#define G4 256   // 4*HID gates
#define TS 128   // timesteps per block in the projection kernel

// ---------------- Kernel 1: xz2[t][unit][4] = gates (i,f,g,o) of unit ----------------
__global__ __launch_bounds__(256, 1) void xz_kernel(
    const float* __restrict__ x, const float* __restrict__ W_ih,
    const float* __restrict__ b_ih, const float* __restrict__ b_hh,
    float* __restrict__ xz2) {
    __shared__ __align__(16) float xs[TS * 100];   // padded rows: 400 B stride
    const int g  = threadIdx.x;                    // gate row 0..255
    const int t0 = blockIdx.x * TS;
    const int unit = g & 63, d = g >> 6;           // transposed write position

    for (int i = g; i < TS * NIN; i += 256) {
        int tl = i / NIN;
        int j  = i - tl * NIN;
        xs[tl * 100 + j] = x[(size_t)t0 * NIN + i];
    }

    float w[NIN];
#pragma unroll
    for (int j = 0; j < NIN; ++j) w[j] = W_ih[g * NIN + j];
    const float bias = b_ih[g] + b_hh[g];
    __syncthreads();

    for (int tl = 0; tl < TS; ++tl) {
        const float* xr = &xs[tl * 100];
        float a0 = bias, a1 = 0.f, a2 = 0.f, a3 = 0.f;
#pragma unroll
        for (int j4 = 0; j4 < 24; ++j4) {
            float4 xv = *(const float4*)(xr + 4 * j4);
            a0 = fmaf(w[4 * j4 + 0], xv.x, a0);
            a1 = fmaf(w[4 * j4 + 1], xv.y, a1);
            a2 = fmaf(w[4 * j4 + 2], xv.z, a2);
            a3 = fmaf(w[4 * j4 + 3], xv.w, a3);
        }
        a0 = fmaf(w[96], xr[96], a0);
        a1 = fmaf(w[97], xr[97], a1);
        a2 = fmaf(w[98], xr[98], a2);
        xz2[(size_t)(t0 + tl) * G4 + unit * 4 + d] = (a0 + a1) + (a2 + a3);
    }
}

// ---------------- Kernel 2: full-asm split-K LSTM recurrence ----------------
// R10 skeleton with the SGPR hazards removed:
//   - lane selects s40-s55 preloaded ONCE (never rewritten in the loop)
//   - 16 readlanes issued back-to-back into 16 distinct dests s56-s71
//   - consumers start 16 instrs later -> zero wait states
// Registers: v100-163 weights (i/f/g/o x16), v196 h, v197 c, v199 z-ptr,
// v200-203 accumulators, v204-215 partner partials, v216-221 act scratch,
// v224-239 z prefetch ring (4 steps deep, vmcnt(3) discipline).

#define G4A(SH, RI, RF, RG, RO) \
  "v_fmac_f32 v200, " SH ", " RI "\n\t" \
  "v_fmac_f32 v201, " SH ", " RF "\n\t" \
  "v_fmac_f32 v202, " SH ", " RG "\n\t" \
  "v_fmac_f32 v203, " SH ", " RO "\n\t"

#define PHASE1 \
  "v_readlane_b32 s56, v196, s40\n\t" \
  "v_readlane_b32 s57, v196, s41\n\t" \
  "v_readlane_b32 s58, v196, s42\n\t" \
  "v_readlane_b32 s59, v196, s43\n\t" \
  "v_readlane_b32 s60, v196, s44\n\t" \
  "v_readlane_b32 s61, v196, s45\n\t" \
  "v_readlane_b32 s62, v196, s46\n\t" \
  "v_readlane_b32 s63, v196, s47\n\t" \
  "v_readlane_b32 s64, v196, s48\n\t" \
  "v_readlane_b32 s65, v196, s49\n\t" \
  "v_readlane_b32 s66, v196, s50\n\t" \
  "v_readlane_b32 s67, v196, s51\n\t" \
  "v_readlane_b32 s68, v196, s52\n\t" \
  "v_readlane_b32 s69, v196, s53\n\t" \
  "v_readlane_b32 s70, v196, s54\n\t" \
  "v_readlane_b32 s71, v196, s55\n\t" \
  "v_mul_f32 v200, s56, v100\n\t" \
  "v_mul_f32 v201, s56, v116\n\t" \
  "v_mul_f32 v202, s56, v132\n\t" \
  "v_mul_f32 v203, s56, v148\n\t" \
  G4A("s57","v101","v117","v133","v149") \
  G4A("s58","v102","v118","v134","v150") \
  G4A("s59","v103","v119","v135","v151") \
  G4A("s60","v104","v120","v136","v152") \
  G4A("s61","v105","v121","v137","v153") \
  G4A("s62","v106","v122","v138","v154") \
  G4A("s63","v107","v123","v139","v155") \
  G4A("s64","v108","v124","v140","v156") \
  G4A("s65","v109","v125","v141","v157") \
  G4A("s66","v110","v126","v142","v158") \
  G4A("s67","v111","v127","v143","v159") \
  G4A("s68","v112","v128","v144","v160") \
  G4A("s69","v113","v129","v145","v161") \
  G4A("s70","v114","v130","v146","v162") \
  G4A("s71","v115","v131","v147","v163")

#define PHASE2(OFS, ZQ, Z0, Z1, Z2, Z3) \
  "ds_write_b128 %[wa], v[200:203] offset:" OFS "\n\t" \
  "s_waitcnt lgkmcnt(0)\n\t" \
  "s_barrier\n\t" \
  "ds_read_b128 v[204:207], %[ra0] offset:" OFS "\n\t" \
  "ds_read_b128 v[208:211], %[ra1] offset:" OFS "\n\t" \
  "ds_read_b128 v[212:215], %[ra2] offset:" OFS "\n\t" \
  "s_waitcnt vmcnt(3)\n\t" \
  "v_add_f32 v200, v200, " Z0 "\n\t" \
  "v_add_f32 v201, v201, " Z1 "\n\t" \
  "v_add_f32 v202, v202, " Z2 "\n\t" \
  "v_add_f32 v203, v203, " Z3 "\n\t" \
  "global_load_dwordx4 " ZQ ", v199, %[zb]\n\t" \
  "v_add_u32 v199, 0x400, v199\n\t" \
  "v_cmp_gt_u32 vcc, 0x4000000, v199\n\t" \
  "v_cndmask_b32 v199, %[zoff], v199, vcc\n\t" \
  "s_waitcnt lgkmcnt(0)\n\t" \
  "v_add_f32 v200, v200, v204\n\t" \
  "v_add_f32 v201, v201, v205\n\t" \
  "v_add_f32 v202, v202, v206\n\t" \
  "v_add_f32 v203, v203, v207\n\t" \
  "v_add_f32 v200, v200, v208\n\t" \
  "v_add_f32 v201, v201, v209\n\t" \
  "v_add_f32 v202, v202, v210\n\t" \
  "v_add_f32 v203, v203, v211\n\t" \
  "v_add_f32 v200, v200, v212\n\t" \
  "v_add_f32 v201, v201, v213\n\t" \
  "v_add_f32 v202, v202, v214\n\t" \
  "v_add_f32 v203, v203, v215\n\t" \
  "v_mul_f32 v216, 0xbfb8aa3b, v200\n\t" \
  "v_mul_f32 v217, 0xbfb8aa3b, v201\n\t" \
  "v_mul_f32 v218, 0xbfb8aa3b, v203\n\t" \
  "v_and_b32 v219, 0x7fffffff, v202\n\t" \
  "v_exp_f32 v216, v216\n\t" \
  "v_exp_f32 v217, v217\n\t" \
  "v_exp_f32 v218, v218\n\t" \
  "v_mul_f32 v219, 0x4038aa3b, v219\n\t" \
  "v_exp_f32 v219, v219\n\t" \
  "v_add_f32 v216, 1.0, v216\n\t" \
  "v_add_f32 v217, 1.0, v217\n\t" \
  "v_add_f32 v218, 1.0, v218\n\t" \
  "v_add_f32 v219, 1.0, v219\n\t" \
  "v_rcp_f32 v216, v216\n\t" \
  "v_rcp_f32 v217, v217\n\t" \
  "v_rcp_f32 v219, v219\n\t" \
  "v_rcp_f32 v218, v218\n\t" \
  "v_fma_f32 v219, -2.0, v219, 1.0\n\t" \
  "v_bfi_b32 v219, s84, v202, v219\n\t" \
  "v_mul_f32 v220, v216, v219\n\t" \
  "v_fma_f32 v197, v217, v197, v220\n\t" \
  "v_and_b32 v221, 0x7fffffff, v197\n\t" \
  "v_mul_f32 v221, 0x4038aa3b, v221\n\t" \
  "v_exp_f32 v221, v221\n\t" \
  "s_nop 0\n\t" \
  "v_add_f32 v221, 1.0, v221\n\t" \
  "v_rcp_f32 v221, v221\n\t" \
  "s_nop 0\n\t" \
  "v_fma_f32 v221, -2.0, v221, 1.0\n\t" \
  "v_bfi_b32 v221, s84, v197, v221\n\t" \
  "v_mul_f32 v196, v218, v221\n\t"

__global__ __launch_bounds__(256, 1) __attribute__((amdgpu_waves_per_eu(1)))
void lstm_kernel(
    const float* __restrict__ xz2, const float* __restrict__ W_hh,
    const float* __restrict__ W1, const float* __restrict__ W2,
    const float* __restrict__ b2, float* __restrict__ out) {
    __shared__ __align__(16) float pbuf[2][4][HID][4];   // [parity][chunk][unit][gate]
    __shared__ float hfin[HID];
    __shared__ float hbuf[32];
    const int tid = threadIdx.x;
    const int l   = tid & 63;
    const int wv  = tid >> 6;

    // byte offsets / addresses for the asm block
    unsigned woff = (unsigned)(l * 256 + wv * 64);      // W_hh: row l, col 16wv
    unsigned zoff = (unsigned)(l * 16);                 // xz2: unit l's float4
    unsigned lbase = (unsigned)(size_t)&pbuf[0][0][0][0];
    unsigned wa  = lbase + (unsigned)((wv * 64 + l) * 16);
    unsigned ra0 = lbase + (unsigned)((((wv + 1) & 3) * 64 + l) * 16);
    unsigned ra1 = lbase + (unsigned)((((wv + 2) & 3) * 64 + l) * 16);
    unsigned ra2 = lbase + (unsigned)((((wv + 3) & 3) * 64 + l) * 16);
    int ssb = __builtin_amdgcn_readfirstlane(16 * wv);  // k-chunk base lane

    float h;
    asm volatile(
        // ---- prologue ----
        "v_mov_b32 v196, 0\n\t"
        "v_mov_b32 v197, 0\n\t"
        "s_mov_b32 s84, 0x80000000\n\t"
        // lane-select constants s40..s55 = sb+0..sb+15 (never rewritten)
        "s_mov_b32 s40, %[sb]\n\t"
        "s_add_u32 s41, s40, 1\n\t"
        "s_add_u32 s42, s40, 2\n\t"
        "s_add_u32 s43, s40, 3\n\t"
        "s_add_u32 s44, s40, 4\n\t"
        "s_add_u32 s45, s40, 5\n\t"
        "s_add_u32 s46, s40, 6\n\t"
        "s_add_u32 s47, s40, 7\n\t"
        "s_add_u32 s48, s40, 8\n\t"
        "s_add_u32 s49, s40, 9\n\t"
        "s_add_u32 s50, s40, 10\n\t"
        "s_add_u32 s51, s40, 11\n\t"
        "s_add_u32 s52, s40, 12\n\t"
        "s_add_u32 s53, s40, 13\n\t"
        "s_add_u32 s54, s40, 14\n\t"
        "s_add_u32 s55, s40, 15\n\t"
        // weights
        "v_mov_b32 v199, %[woff]\n\t"
        "global_load_dwordx4 v[100:103], v199, %[wb]\n\t"
        "global_load_dwordx4 v[104:107], v199, %[wb] offset:16\n\t"
        "global_load_dwordx4 v[108:111], v199, %[wb] offset:32\n\t"
        "global_load_dwordx4 v[112:115], v199, %[wb] offset:48\n\t"
        "v_add_u32 v199, 0x4000, v199\n\t"
        "global_load_dwordx4 v[116:119], v199, %[wb]\n\t"
        "global_load_dwordx4 v[120:123], v199, %[wb] offset:16\n\t"
        "global_load_dwordx4 v[124:127], v199, %[wb] offset:32\n\t"
        "global_load_dwordx4 v[128:131], v199, %[wb] offset:48\n\t"
        "v_add_u32 v199, 0x4000, v199\n\t"
        "global_load_dwordx4 v[132:135], v199, %[wb]\n\t"
        "global_load_dwordx4 v[136:139], v199, %[wb] offset:16\n\t"
        "global_load_dwordx4 v[140:143], v199, %[wb] offset:32\n\t"
        "global_load_dwordx4 v[144:147], v199, %[wb] offset:48\n\t"
        "v_add_u32 v199, 0x4000, v199\n\t"
        "global_load_dwordx4 v[148:151], v199, %[wb]\n\t"
        "global_load_dwordx4 v[152:155], v199, %[wb] offset:16\n\t"
        "global_load_dwordx4 v[156:159], v199, %[wb] offset:32\n\t"
        "global_load_dwordx4 v[160:163], v199, %[wb] offset:48\n\t"
        // z prefetch ring
        "v_mov_b32 v199, %[zoff]\n\t"
        "global_load_dwordx4 v[224:227], v199, %[zb]\n\t"
        "global_load_dwordx4 v[228:231], v199, %[zb] offset:1024\n\t"
        "global_load_dwordx4 v[232:235], v199, %[zb] offset:2048\n\t"
        "global_load_dwordx4 v[236:239], v199, %[zb] offset:3072\n\t"
        "v_add_u32 v199, 0x1000, v199\n\t"
        "s_waitcnt vmcnt(4)\n\t"            // weights resident; z ring in flight
        "s_mov_b32 s85, 0x4000\n\t"         // 16384 iterations x 4 steps
        "Lk%=:\n\t"
        PHASE1 PHASE2("0",    "v[224:227]", "v224", "v225", "v226", "v227")
        PHASE1 PHASE2("4096", "v[228:231]", "v228", "v229", "v230", "v231")
        PHASE1 PHASE2("0",    "v[232:235]", "v232", "v233", "v234", "v235")
        PHASE1 PHASE2("4096", "v[236:239]", "v236", "v237", "v238", "v239")
        "s_sub_u32 s85, s85, 1\n\t"
        "s_cmp_lg_u32 s85, 0\n\t"
        "s_cbranch_scc1 Lk%=\n\t"
        "v_mov_b32 %[hout], v196\n\t"
        : [hout]"=v"(h)
        : [wb]"s"(W_hh), [zb]"s"(xz2), [sb]"s"(ssb),
          [woff]"v"(woff), [zoff]"v"(zoff),
          [wa]"v"(wa), [ra0]"v"(ra0), [ra1]"v"(ra1), [ra2]"v"(ra2)
        : "memory", "vcc",
          "s40","s41","s42","s43","s44","s45","s46","s47",
          "s48","s49","s50","s51","s52","s53","s54","s55",
          "s56","s57","s58","s59","s60","s61","s62","s63",
          "s64","s65","s66","s67","s68","s69","s70","s71",
          "s84","s85",
          "v100","v101","v102","v103","v104","v105","v106","v107",
          "v108","v109","v110","v111","v112","v113","v114","v115",
          "v116","v117","v118","v119","v120","v121","v122","v123",
          "v124","v125","v126","v127","v128","v129","v130","v131",
          "v132","v133","v134","v135","v136","v137","v138","v139",
          "v140","v141","v142","v143","v144","v145","v146","v147",
          "v148","v149","v150","v151","v152","v153","v154","v155",
          "v156","v157","v158","v159","v160","v161","v162","v163",
          "v196","v197","v198","v199",
          "v200","v201","v202","v203","v204","v205","v206","v207",
          "v208","v209","v210","v211","v212","v213","v214","v215",
          "v216","v217","v218","v219","v220","v221","v222","v223",
          "v224","v225","v226","v227","v228","v229","v230","v231",
          "v232","v233","v234","v235","v236","v237","v238","v239");

    // head: out = W2 @ relu(W1 @ relu(h_T)) + b2
    if (tid < HID) hfin[tid] = h;
    __syncthreads();
    if (tid < 32) {
        float s = 0.0f;
#pragma unroll
        for (int j = 0; j < HID; ++j) s += W1[tid * HID + j] * fmaxf(hfin[j], 0.0f);
        hbuf[tid] = fmaxf(s, 0.0f);
    }
    __syncthreads();
    if (tid < 3) {
        float s = b2[tid];
#pragma unroll
        for (int j = 0; j < 32; ++j) s += W2[tid * 32 + j] * hbuf[j];
        out[tid] = s;
    }
}

extern "C" void kernel_launch(void* const* d_in, const int* in_sizes, int n_in,
                              void* d_out, int out_size, void* d_ws, size_t ws_size,
                              hipStream_t stream) {
    const float* x   = (const float*)d_in[0];
    const float* Wih = (const float*)d_in[1];
    const float* Whh = (const float*)d_in[2];
    const float* bih = (const float*)d_in[3];
    const float* bhh = (const float*)d_in[4];
    const float* W1  = (const float*)d_in[5];
    const float* W2  = (const float*)d_in[6];
    const float* b2  = (const float*)d_in[7];
    float* out = (float*)d_out;
    float* xz2 = (float*)d_ws;   // T_STEPS * 256 floats = 64 MB (transposed layout)

    xz_kernel<<<T_STEPS / TS, 256, 0, stream>>>(x, Wih, bih, bhh, xz2);
    lstm_kernel<<<1, 256, 0, stream>>>(xz2, Whh, W1, W2, b2, out);
}